// Round 6
// baseline (413021.387 us; speedup 1.0000x reference)
//
#include <hip/hip_runtime.h>
#include <math.h>

#define N 2048
#define DIMS 784
#define BIGV 1.0e6f
#define NC 784

#define NB 64
#define NPAIRS 32
#define NSWEEPS 16
#define INNER_MAX 2

__device__ __forceinline__ void rr_pair(int r, int m, int& bi, int& bj) {
    if (m == 0) { bi = 63; bj = r % 63; }
    else { bi = (r + m) % 63; bj = (r - m + 63) % 63; }
}

// ---------------- distances ----------------
__global__ void k_rowsq(const float* __restrict__ X, float* __restrict__ sq) {
    int wave = threadIdx.x >> 6, lane = threadIdx.x & 63;
    int row = blockIdx.x * 4 + wave;
    const float* xr = X + (size_t)row * DIMS;
    float s = 0.f;
    for (int k = lane; k < DIMS; k += 64) { float v = xr[k]; s += v * v; }
    for (int off = 32; off; off >>= 1) s += __shfl_down(s, off);
    if (lane == 0) sq[row] = s;
}

__global__ void __launch_bounds__(256) k_dist(const float* __restrict__ X,
                                              const float* __restrict__ sq,
                                              float* __restrict__ out) {
    __shared__ float As[64][17], Bs[64][17];
    int ti = blockIdx.y, tj = blockIdx.x, t = threadIdx.x;
    int tx = t & 15, ty = t >> 4;
    float acc[4][4] = {};
    for (int k0 = 0; k0 < DIMS; k0 += 16) {
        for (int e = 0; e < 4; e++) {
            int idx = t + e * 256; int r = idx >> 4, c = idx & 15;
            As[r][c] = X[(size_t)(ti * 64 + r) * DIMS + k0 + c];
            Bs[r][c] = X[(size_t)(tj * 64 + r) * DIMS + k0 + c];
        }
        __syncthreads();
        for (int k = 0; k < 16; k++) {
            float a[4], b[4];
            for (int e = 0; e < 4; e++) a[e] = As[ty * 4 + e][k];
            for (int f = 0; f < 4; f++) b[f] = Bs[tx * 4 + f][k];
            for (int e = 0; e < 4; e++)
                for (int f = 0; f < 4; f++) acc[e][f] += a[e] * b[f];
        }
        __syncthreads();
    }
    for (int e = 0; e < 4; e++)
        for (int f = 0; f < 4; f++) {
            int gi = ti * 64 + ty * 4 + e, gj = tj * 64 + tx * 4 + f;
            float d2 = sq[gi] + sq[gj] - 2.f * acc[e][f];
            out[(size_t)gi * N + gj] = sqrtf(fmaxf(d2, 0.f));
        }
}

// ---------------- KNN graph ----------------
__global__ void k_knn(const float* __restrict__ dist, float* __restrict__ G) {
    int i = blockIdx.x, t = threadIdx.x;
    float bv[6]; int bidx[6];
    for (int k = 0; k < 6; k++) { bv[k] = 3.4e38f; bidx[k] = N; }
    const float* dr = dist + (size_t)i * N;
    for (int j = t; j < N; j += 256) {
        float v = dr[j];
        bool ins = (v < bv[5]) || (v == bv[5] && j < bidx[5]);
        if (ins) {
            int k = 5;
            while (k > 0) {
                bool mv = (v < bv[k - 1]) || (v == bv[k - 1] && j < bidx[k - 1]);
                if (!mv) break;
                bv[k] = bv[k - 1]; bidx[k] = bidx[k - 1]; k--;
            }
            bv[k] = v; bidx[k] = j;
        }
    }
    __shared__ float lv[256][6]; __shared__ int li[256][6];
    for (int k = 0; k < 6; k++) { lv[t][k] = bv[k]; li[t][k] = bidx[k]; }
    __syncthreads();
    for (int off = 128; off >= 1; off >>= 1) {
        if (t < off) {
            float av[6], cv[6]; int ai[6], ci[6];
            for (int k = 0; k < 6; k++) { av[k] = lv[t][k]; ai[k] = li[t][k]; cv[k] = lv[t + off][k]; ci[k] = li[t + off][k]; }
            float mv[6]; int mi[6]; int pa = 0, pb = 0;
            for (int k = 0; k < 6; k++) {
                bool ta;
                if (pa >= 6) ta = false;
                else if (pb >= 6) ta = true;
                else ta = (av[pa] < cv[pb]) || (av[pa] == cv[pb] && ai[pa] < ci[pb]);
                if (ta) { mv[k] = av[pa]; mi[k] = ai[pa]; pa++; }
                else    { mv[k] = cv[pb]; mi[k] = ci[pb]; pb++; }
            }
            for (int k = 0; k < 6; k++) { lv[t][k] = mv[k]; li[t][k] = mi[k]; }
        }
        __syncthreads();
    }
    float sv[6]; int si[6];
    for (int k = 0; k < 6; k++) { sv[k] = lv[0][k]; si[k] = li[0][k]; }
    for (int j = t; j < N; j += 256) {
        float val = BIGV;
        for (int k = 0; k < 6; k++) if (j == si[k]) val = sv[k];
        G[(size_t)i * N + j] = val;
    }
}

__global__ void k_symdiag(float* __restrict__ G) {
    int idx = blockIdx.x * 256 + threadIdx.x;
    int i = idx >> 11, j = idx & 2047;
    if (i == j) { G[idx] = 0.f; return; }
    if (j > i) {
        float a = G[(size_t)i * N + j], b = G[(size_t)j * N + i];
        float m = fminf(a, b);
        G[(size_t)i * N + j] = m; G[(size_t)j * N + i] = m;
    }
}

// ---------------- blocked Floyd-Warshall ----------------
__global__ void __launch_bounds__(256) k_fw12(float* __restrict__ D, int kb) {
    __shared__ float KK[64][65], C[64][65];
    int bx = blockIdx.x, t = threadIdx.x;
    for (int e = 0; e < 16; e++) { int idx = t + e * 256; int r = idx >> 6, c = idx & 63;
        KK[r][c] = D[(size_t)(kb * 64 + r) * N + kb * 64 + c]; }
    __syncthreads();
    int r0 = t >> 2, c0 = (t & 3) * 16;
    for (int k = 0; k < 64; k++) {
        float dk = KK[r0][k];
        for (int c = 0; c < 16; c++) KK[r0][c0 + c] = fminf(KK[r0][c0 + c], dk + KK[k][c0 + c]);
        __syncthreads();
    }
    if (bx == 62) {
        for (int e = 0; e < 16; e++) { int idx = t + e * 256; int r = idx >> 6, c = idx & 63;
            D[(size_t)(kb * 64 + r) * N + kb * 64 + c] = KK[r][c]; }
        return;
    }
    bool rowstripe = bx < 31;
    int o = rowstripe ? bx : bx - 31;
    o += (o >= kb) ? 1 : 0;
    int baseR = rowstripe ? kb : o;
    int baseC = rowstripe ? o : kb;
    for (int e = 0; e < 16; e++) { int idx = t + e * 256; int r = idx >> 6, c = idx & 63;
        C[r][c] = D[(size_t)(baseR * 64 + r) * N + baseC * 64 + c]; }
    __syncthreads();
    if (rowstripe) {
        for (int k = 0; k < 64; k++) {
            float dk = KK[r0][k];
            for (int c = 0; c < 16; c++) C[r0][c0 + c] = fminf(C[r0][c0 + c], dk + C[k][c0 + c]);
            __syncthreads();
        }
    } else {
        for (int k = 0; k < 64; k++) {
            float dk = C[r0][k];
            for (int c = 0; c < 16; c++) C[r0][c0 + c] = fminf(C[r0][c0 + c], dk + KK[k][c0 + c]);
            __syncthreads();
        }
    }
    for (int e = 0; e < 16; e++) { int idx = t + e * 256; int r = idx >> 6, c = idx & 63;
        D[(size_t)(baseR * 64 + r) * N + baseC * 64 + c] = C[r][c]; }
}

__global__ void __launch_bounds__(256) k_fw3(float* __restrict__ D, int kb) {
    int bi = blockIdx.y, bj = blockIdx.x;
    if (bi == kb || bj == kb) return;
    __shared__ float R[64][65], Cl[64][65];
    int t = threadIdx.x;
    for (int e = 0; e < 16; e++) { int idx = t + e * 256; int r = idx >> 6, c = idx & 63;
        R[r][c]  = D[(size_t)(bi * 64 + r) * N + kb * 64 + c];
        Cl[r][c] = D[(size_t)(kb * 64 + r) * N + bj * 64 + c]; }
    __syncthreads();
    int r0 = (t >> 4) * 4, c0 = (t & 15) * 4;
    float acc[4][4];
    for (int e = 0; e < 4; e++) for (int f = 0; f < 4; f++) acc[e][f] = 3.4e38f;
    for (int k = 0; k < 64; k++) {
        float a[4], b[4];
        for (int e = 0; e < 4; e++) a[e] = R[r0 + e][k];
        for (int f = 0; f < 4; f++) b[f] = Cl[k][c0 + f];
        for (int e = 0; e < 4; e++)
            for (int f = 0; f < 4; f++) acc[e][f] = fminf(acc[e][f], a[e] + b[f]);
    }
    for (int e = 0; e < 4; e++)
        for (int f = 0; f < 4; f++) {
            size_t off = (size_t)(bi * 64 + r0 + e) * N + bj * 64 + c0 + f;
            D[off] = fminf(D[off], acc[e][f]);
        }
}

// ---------------- double centering ----------------
__global__ void k_rowmean(const float* __restrict__ D, double* __restrict__ rm) {
    int i = blockIdx.x, t = threadIdx.x;
    const float* dr = D + (size_t)i * N;
    double s = 0;
    for (int j = t; j < N; j += 256) { double d = (double)dr[j]; s += d * d; }
    __shared__ double red[256];
    red[t] = s; __syncthreads();
    for (int off = 128; off; off >>= 1) { if (t < off) red[t] += red[t + off]; __syncthreads(); }
    if (t == 0) rm[i] = red[0] / (double)N;
}

__global__ void k_grand(const double* __restrict__ rm, double* __restrict__ gm) {
    int t = threadIdx.x;
    double s = 0;
    for (int i = t; i < N; i += 256) s += rm[i];
    __shared__ double red[256];
    red[t] = s; __syncthreads();
    for (int off = 128; off; off >>= 1) { if (t < off) red[t] += red[t + off]; __syncthreads(); }
    if (t == 0) gm[0] = red[0] / (double)N;
}

__global__ void k_buildB(const float* __restrict__ D, const double* __restrict__ rm,
                         const double* __restrict__ gm, double* __restrict__ A) {
    int idx = blockIdx.x * 256 + threadIdx.x;
    int i = idx >> 11, j = idx & 2047;
    double d = (double)D[idx];
    A[idx] = -0.5 * (d * d - rm[i] - rm[j] + gm[0]);
}

__global__ void k_setV(float* __restrict__ V) {
    int idx = blockIdx.x * 256 + threadIdx.x;
    int i = idx >> 11, j = idx & 2047;
    V[idx] = (i == j) ? 1.f : 0.f;
}

__global__ void k_init(unsigned* flags, unsigned* bar) {
    flags[0] = 0u; flags[1] = 0u; flags[2] = 0u;
    bar[0] = 0u; bar[1] = 0u;
}

// ---------------- persistent block-Jacobi ----------------
union Smem {
    struct { double M[64][65]; double Q[64][65]; } L;
    struct { double T[64][65]; double Qb[64][65]; } Ap;
    struct { float Qs[64][65]; float Tv[64][65]; } Vp;
};

__device__ __forceinline__ void gridbar(unsigned* bar, int nb) {
    __syncthreads();
    if (threadIdx.x == 0) {
        __threadfence();
        unsigned g = __hip_atomic_load(&bar[1], __ATOMIC_RELAXED, __HIP_MEMORY_SCOPE_AGENT);
        unsigned a = __hip_atomic_fetch_add(&bar[0], 1u, __ATOMIC_ACQ_REL, __HIP_MEMORY_SCOPE_AGENT);
        if (a == (unsigned)(nb - 1)) {
            __hip_atomic_store(&bar[0], 0u, __ATOMIC_RELAXED, __HIP_MEMORY_SCOPE_AGENT);
            __hip_atomic_store(&bar[1], g + 1u, __ATOMIC_RELEASE, __HIP_MEMORY_SCOPE_AGENT);
        } else {
            while (__hip_atomic_load(&bar[1], __ATOMIC_ACQUIRE, __HIP_MEMORY_SCOPE_AGENT) == g)
                __builtin_amdgcn_s_sleep(1);
        }
        __threadfence();
    }
    __syncthreads();
}

__global__ void __launch_bounds__(256) k_jacobi(double* __restrict__ A, float* __restrict__ V,
                                                double* __restrict__ qb, int* __restrict__ qfl,
                                                unsigned* flags, unsigned* bar, int nb) {
    __shared__ Smem sm;
    __shared__ double cA[32], sA[32];
    __shared__ int ppA[32], qqA[32];
    __shared__ float red1[256], red2[256];
    __shared__ int anyr, everr;
    int t = threadIdx.x;
    int stride = nb >> 8;                      // nb is 256 or 512
    bool isLocal = (blockIdx.x < 32 * stride) && ((blockIdx.x % stride) == 0);
    int myPair = blockIdx.x / stride;

    for (int sw = 0; sw < NSWEEPS; sw++) {
        if (blockIdx.x == 0 && t == 0) { flags[0] = 0u; flags[1] = 0u; }
        gridbar(bar, nb);
        for (int r = 0; r < 63; r++) {
            // ---- local phase ----
            if (isLocal) {
                int p = myPair;
                int bi, bj; rr_pair(r, p, bi, bj);
                float offm = 0.f, diagm = 0.f;
                for (int e = 0; e < 16; e++) {
                    int idx = t + e * 256; int x = idx >> 6, y = idx & 63;
                    int gr = (x < 32) ? bi * 32 + x : bj * 32 + (x - 32);
                    int gc = (y < 32) ? bi * 32 + y : bj * 32 + (y - 32);
                    double v = A[(size_t)gr * N + gc];
                    sm.L.M[x][y] = v;
                    float av = (float)fabs(v);
                    if (x == y) diagm = fmaxf(diagm, av); else offm = fmaxf(offm, av);
                    sm.L.Q[x][y] = (x == y) ? 1.0 : 0.0;
                }
                red1[t] = offm; red2[t] = diagm;
                if (t == 0) { anyr = 0; everr = 0; }
                __syncthreads();
                for (int off = 128; off; off >>= 1) {
                    if (t < off) { red1[t] = fmaxf(red1[t], red1[t + off]); red2[t] = fmaxf(red2[t], red2[t + off]); }
                    __syncthreads();
                }
                float dmaxf = red2[0], off0 = red1[0];
                if (t == 0) { atomicMax(flags + 0, __float_as_uint(off0)); atomicMax(flags + 1, __float_as_uint(dmaxf)); }
                double dmax = (double)dmaxf;
                if ((double)off0 <= 1e-9 * dmax) {
                    if (t == 0) qfl[p] = 0;
                } else {
                    double thr = fmax(1e-13 * dmax, 1e-5 * (double)off0);
                    for (int s = 0; s < INNER_MAX; s++) {
                        if (t == 0) anyr = 0;
                        __syncthreads();
                        for (int ir = 0; ir < 63; ir++) {
                            if (t < 32) {
                                int pp, qq; rr_pair(ir, t, pp, qq);
                                double app = sm.L.M[pp][pp], aqq = sm.L.M[qq][qq], apq = sm.L.M[pp][qq];
                                double c = 1.0, sn = 0.0;
                                if (fabs(apq) > thr) {
                                    double tau = (aqq - app) / (2.0 * apq);
                                    double tt = ((tau >= 0.0) ? 1.0 : -1.0) / (fabs(tau) + sqrt(1.0 + tau * tau));
                                    c = 1.0 / sqrt(1.0 + tt * tt);
                                    sn = tt * c;
                                    anyr = 1; everr = 1;
                                }
                                ppA[t] = pp; qqA[t] = qq; cA[t] = c; sA[t] = sn;
                            }
                            __syncthreads();
                            // fused quad update: M <- J^T M J (in-place, disjoint quads)
                            for (int e = 0; e < 4; e++) {
                                int idx = t + e * 256; int a = idx >> 5, b = idx & 31;
                                double sa_ = sA[a], sb_ = sA[b];
                                if (sa_ != 0.0 || sb_ != 0.0) {
                                    int pa = ppA[a], qa = qqA[a], pb = ppA[b], qb2 = qqA[b];
                                    double ca = cA[a], cb = cA[b];
                                    double m00 = sm.L.M[pa][pb], m01 = sm.L.M[pa][qb2];
                                    double m10 = sm.L.M[qa][pb], m11 = sm.L.M[qa][qb2];
                                    double t00 = cb * m00 - sb_ * m01, t01 = sb_ * m00 + cb * m01;
                                    double t10 = cb * m10 - sb_ * m11, t11 = sb_ * m10 + cb * m11;
                                    sm.L.M[pa][pb] = ca * t00 - sa_ * t10; sm.L.M[pa][qb2] = ca * t01 - sa_ * t11;
                                    sm.L.M[qa][pb] = sa_ * t00 + ca * t10; sm.L.M[qa][qb2] = sa_ * t01 + ca * t11;
                                }
                            }
                            // Q <- Q J (column pairs, in-place, disjoint)
                            for (int e = 0; e < 8; e++) {
                                int idx = t + e * 256; int k = idx >> 5, b = idx & 31;
                                double sb_ = sA[b];
                                if (sb_ != 0.0) {
                                    int pb = ppA[b], qb2 = qqA[b]; double cb = cA[b];
                                    double q0 = sm.L.Q[k][pb], q1 = sm.L.Q[k][qb2];
                                    sm.L.Q[k][pb] = cb * q0 - sb_ * q1; sm.L.Q[k][qb2] = sb_ * q0 + cb * q1;
                                }
                            }
                            __syncthreads();
                        }
                        int cont = anyr;
                        __syncthreads();
                        if (!cont) break;
                    }
                    __syncthreads();
                    int ev = everr;
                    if (t == 0) qfl[p] = ev;
                    if (ev) {
                        for (int e = 0; e < 16; e++) {
                            int idx = t + e * 256; int x = idx >> 6, y = idx & 63;
                            qb[(size_t)p * 4096 + idx] = sm.L.Q[x][y];
                            int gr = (x < 32) ? bi * 32 + x : bj * 32 + (x - 32);
                            int gc = (y < 32) ? bi * 32 + y : bj * 32 + (y - 32);
                            A[(size_t)gr * N + gc] = sm.L.M[x][y];
                        }
                    }
                }
            }
            gridbar(bar, nb);
            // ---- apply phase: 2048 task slots ----
            for (int tid = blockIdx.x; tid < 2048; tid += nb) {
                if (tid < 1024) {
                    int pr = tid >> 5, pc = tid & 31;
                    if (pr >= pc) continue;
                    int fr = qfl[pr], fc = qfl[pc];
                    if (!fr && !fc) continue;
                    int bir, bjr, bic, bjc;
                    rr_pair(r, pr, bir, bjr);
                    rr_pair(r, pc, bic, bjc);
                    __syncthreads();
                    for (int e = 0; e < 16; e++) {
                        int idx = t + e * 256; int a = idx >> 6, b = idx & 63;
                        if (fr) sm.Ap.Qb[a][b] = qb[(size_t)pr * 4096 + idx];
                        int gr = (a < 32) ? bir * 32 + a : bjr * 32 + (a - 32);
                        int gc = (b < 32) ? bic * 32 + b : bjc * 32 + (b - 32);
                        sm.Ap.T[a][b] = A[(size_t)gr * N + gc];
                    }
                    __syncthreads();
                    int x0 = (t >> 4) * 4, c0 = (t & 15) * 4;
                    if (fr) {
                        double acc[4][4] = {};
                        for (int y = 0; y < 64; y++) {
                            double q[4], v[4];
                            for (int e = 0; e < 4; e++) q[e] = sm.Ap.Qb[y][x0 + e];
                            for (int f = 0; f < 4; f++) v[f] = sm.Ap.T[y][c0 + f];
                            for (int e = 0; e < 4; e++)
                                for (int f = 0; f < 4; f++) acc[e][f] += q[e] * v[f];
                        }
                        __syncthreads();
                        for (int e = 0; e < 4; e++)
                            for (int f = 0; f < 4; f++) sm.Ap.T[x0 + e][c0 + f] = acc[e][f];
                        __syncthreads();
                    }
                    if (fc) {
                        for (int e = 0; e < 16; e++) {
                            int idx = t + e * 256; int a = idx >> 6, b = idx & 63;
                            sm.Ap.Qb[a][b] = qb[(size_t)pc * 4096 + idx];
                        }
                        __syncthreads();
                        double acc[4][4] = {};
                        for (int y = 0; y < 64; y++) {
                            double v[4], q[4];
                            for (int e = 0; e < 4; e++) v[e] = sm.Ap.T[x0 + e][y];
                            for (int f = 0; f < 4; f++) q[f] = sm.Ap.Qb[y][c0 + f];
                            for (int e = 0; e < 4; e++)
                                for (int f = 0; f < 4; f++) acc[e][f] += v[e] * q[f];
                        }
                        __syncthreads();
                        for (int e = 0; e < 4; e++)
                            for (int f = 0; f < 4; f++) sm.Ap.T[x0 + e][c0 + f] = acc[e][f];
                        __syncthreads();
                    }
                    for (int e = 0; e < 16; e++) {
                        int idx = t + e * 256; int a = idx >> 6, b = idx & 63;
                        int gr = (a < 32) ? bir * 32 + a : bjr * 32 + (a - 32);
                        int gc = (b < 32) ? bic * 32 + b : bjc * 32 + (b - 32);
                        A[(size_t)gr * N + gc] = sm.Ap.T[a][b];
                        int gr2 = (a < 32) ? bic * 32 + a : bjc * 32 + (a - 32);
                        int gc2 = (b < 32) ? bir * 32 + b : bjr * 32 + (b - 32);
                        A[(size_t)gr2 * N + gc2] = sm.Ap.T[b][a];
                    }
                } else {
                    int v = tid - 1024; int p = v >> 5, rt = v & 31;
                    if (!qfl[p]) continue;
                    int bi, bj; rr_pair(r, p, bi, bj);
                    __syncthreads();
                    for (int e = 0; e < 16; e++) {
                        int idx = t + e * 256; int a = idx >> 6, b = idx & 63;
                        sm.Vp.Qs[a][b] = (float)qb[(size_t)p * 4096 + idx];
                        int gc = (b < 32) ? bi * 32 + b : bj * 32 + (b - 32);
                        sm.Vp.Tv[a][b] = V[(size_t)(rt * 64 + a) * N + gc];
                    }
                    __syncthreads();
                    int r0 = (t >> 4) * 4, x0 = (t & 15) * 4;
                    float acc[4][4] = {};
                    for (int y = 0; y < 64; y++) {
                        float vv[4], q[4];
                        for (int e = 0; e < 4; e++) vv[e] = sm.Vp.Tv[r0 + e][y];
                        for (int f = 0; f < 4; f++) q[f] = sm.Vp.Qs[y][x0 + f];
                        for (int e = 0; e < 4; e++)
                            for (int f = 0; f < 4; f++) acc[e][f] += vv[e] * q[f];
                    }
                    for (int e = 0; e < 4; e++)
                        for (int f = 0; f < 4; f++) {
                            int x = x0 + f;
                            int gc = (x < 32) ? bi * 32 + x : bj * 32 + (x - 32);
                            V[(size_t)(rt * 64 + r0 + e) * N + gc] = acc[e][f];
                        }
                }
            }
            gridbar(bar, nb);
        }
        if (blockIdx.x == 0 && t == 0) {
            float mo = __uint_as_float(flags[0]), md = __uint_as_float(flags[1]);
            if (mo <= 2e-9f * md) flags[2] = 1u;
        }
        gridbar(bar, nb);
        if (__hip_atomic_load(&flags[2], __ATOMIC_RELAXED, __HIP_MEMORY_SCOPE_AGENT)) break;
    }
}

// ---------------- epilogue ----------------
__global__ void k_lambda(const double* __restrict__ A, double* __restrict__ lam) {
    int i = blockIdx.x * 256 + threadIdx.x;
    if (i < N) lam[i] = A[(size_t)i * N + i];
}

__global__ void __launch_bounds__(1024) k_sort(const double* __restrict__ lam,
                                               double* __restrict__ lams, int* __restrict__ order) {
    __shared__ double v[2048]; __shared__ int ix[2048];
    int t = threadIdx.x;
    v[t] = lam[t]; v[t + 1024] = lam[t + 1024];
    ix[t] = t; ix[t + 1024] = t + 1024;
    __syncthreads();
    for (int k = 2; k <= 2048; k <<= 1) {
        for (int j = k >> 1; j > 0; j >>= 1) {
            int l = ((t & ~(j - 1)) << 1) | (t & (j - 1));
            int partner = l | j;
            double va = v[l], vb = v[partner]; int ia = ix[l], ib = ix[partner];
            bool before = (va > vb) || (va == vb && ia < ib);
            bool asc = ((l & k) == 0);
            bool doSwap = asc ? (!before) : before;
            if (doSwap) { v[l] = vb; v[partner] = va; ix[l] = ib; ix[partner] = ia; }
            __syncthreads();
        }
    }
    lams[t] = v[t]; lams[t + 1024] = v[t + 1024];
    order[t] = ix[t]; order[t + 1024] = ix[t + 1024];
}

__global__ void k_out(const float* __restrict__ Vm, const double* __restrict__ lams,
                      const int* __restrict__ order, float* __restrict__ out) {
    int c = blockIdx.x, t = threadIdx.x;
    int col = order[c];
    __shared__ float rv[256]; __shared__ int ri[256];
    float bv = -1.f; int bidx = N;
    for (int i = t; i < N; i += 256) {
        float av = fabsf(Vm[(size_t)i * N + col]);
        if (av > bv || (av == bv && i < bidx)) { bv = av; bidx = i; }
    }
    rv[t] = bv; ri[t] = bidx;
    __syncthreads();
    for (int off = 128; off; off >>= 1) {
        if (t < off) {
            if (rv[t + off] > rv[t] || (rv[t + off] == rv[t] && ri[t + off] < ri[t])) {
                rv[t] = rv[t + off]; ri[t] = ri[t + off];
            }
        }
        __syncthreads();
    }
    float sv = Vm[(size_t)ri[0] * N + col];
    float s = (sv > 0.f) ? 1.f : ((sv < 0.f) ? -1.f : 0.f);
    double lv = lams[c];
    float f = s * (float)sqrt(lv > 0.0 ? lv : 0.0);
    for (int i = t; i < N; i += 256) out[(size_t)i * NC + c] = Vm[(size_t)i * N + col] * f;
}

extern "C" void kernel_launch(void* const* d_in, const int* in_sizes, int n_in,
                              void* d_out, int out_size, void* d_ws, size_t ws_size,
                              hipStream_t stream) {
    (void)in_sizes; (void)n_in; (void)out_size; (void)ws_size;
    const float* X = (const float*)d_in[0];
    float* out = (float*)d_out;

    double* rm  = (double*)d_ws;                 // N
    double* gm  = rm + N;                        // 1 (+7 pad)
    double* lam = gm + 8;                        // N
    double* lams= lam + N;                       // N
    double* A   = lams + N;                      // N*N fp64
    double* qb  = A + (size_t)N * N;             // NPAIRS*4096 fp64
    float* Dg   = (float*)(qb + (size_t)NPAIRS * 4096); // N*N f32
    float* Vm   = Dg + (size_t)N * N;            // N*N f32
    float* sq   = Vm + (size_t)N * N;            // N
    int* order  = (int*)(sq + N);                // N
    int* qfl    = order + N;                     // NPAIRS
    unsigned* flags = (unsigned*)(qfl + NPAIRS); // 3
    unsigned* bar   = flags + 4;                 // 2
    float* dist = (float*)A;                     // alias

    // co-residency-safe grid size for the persistent kernel
    int occ = 1;
    if (hipOccupancyMaxActiveBlocksPerMultiprocessor(&occ, k_jacobi, 256, 0) != hipSuccess || occ < 1)
        occ = 1;
    int nb = (occ >= 2) ? 512 : 256;

    // 1. pairwise distances
    k_rowsq<<<N / 4, 256, 0, stream>>>(X, sq);
    k_dist<<<dim3(32, 32), 256, 0, stream>>>(X, sq, dist);

    // 2. KNN graph
    k_knn<<<N, 256, 0, stream>>>(dist, Dg);
    k_symdiag<<<(N * N) / 256, 256, 0, stream>>>(Dg);

    // 3. blocked Floyd-Warshall
    for (int kb = 0; kb < N / 64; kb++) {
        k_fw12<<<63, 256, 0, stream>>>(Dg, kb);
        k_fw3<<<dim3(32, 32), 256, 0, stream>>>(Dg, kb);
    }

    // 4. double centering -> B (fp64)
    k_rowmean<<<N, 256, 0, stream>>>(Dg, rm);
    k_grand<<<1, 256, 0, stream>>>(rm, gm);
    k_buildB<<<(N * N) / 256, 256, 0, stream>>>(Dg, rm, gm, A);
    k_setV<<<(N * N) / 256, 256, 0, stream>>>(Vm);
    k_init<<<1, 1, 0, stream>>>(flags, bar);

    // 5. persistent two-sided block Jacobi (single launch)
    k_jacobi<<<nb, 256, 0, stream>>>(A, Vm, qb, qfl, flags, bar, nb);

    // 6. sort eigenvalues, sign-fix, scale, write output
    k_lambda<<<N / 256, 256, 0, stream>>>(A, lam);
    k_sort<<<1, 1024, 0, stream>>>(lam, lams, order);
    k_out<<<NC, 256, 0, stream>>>(Vm, lams, order, out);
}

// Round 7
// 112170.117 us; speedup vs baseline: 3.6821x; 3.6821x over previous
//
#include <hip/hip_runtime.h>
#include <math.h>

#define N 2048
#define DIMS 784
#define BIGV 1.0e6f
#define NC 784

// two-sided block Jacobi config: 128 teams of width 16, 32x32 local tiles
#define NB 128
#define NPAIRS 64
#define NSWEEPS 20

// round-robin pairing over nteams: round r in [0,nteams-1), pair m in [0,nteams/2)
__device__ __forceinline__ void rr_pairN(int r, int m, int nteams, int& bi, int& bj) {
    int n1 = nteams - 1;
    if (m == 0) { bi = n1; bj = r % n1; }
    else { bi = (r + m) % n1; bj = (r - m + n1) % n1; }
}

// ---------------- distances ----------------
__global__ void k_rowsq(const float* __restrict__ X, float* __restrict__ sq) {
    int wave = threadIdx.x >> 6, lane = threadIdx.x & 63;
    int row = blockIdx.x * 4 + wave;
    const float* xr = X + (size_t)row * DIMS;
    float s = 0.f;
    for (int k = lane; k < DIMS; k += 64) { float v = xr[k]; s += v * v; }
    for (int off = 32; off; off >>= 1) s += __shfl_down(s, off);
    if (lane == 0) sq[row] = s;
}

__global__ void __launch_bounds__(256) k_dist(const float* __restrict__ X,
                                              const float* __restrict__ sq,
                                              float* __restrict__ out) {
    __shared__ float As[64][17], Bs[64][17];
    int ti = blockIdx.y, tj = blockIdx.x, t = threadIdx.x;
    int tx = t & 15, ty = t >> 4;
    float acc[4][4] = {};
    for (int k0 = 0; k0 < DIMS; k0 += 16) {
        for (int e = 0; e < 4; e++) {
            int idx = t + e * 256; int r = idx >> 4, c = idx & 15;
            As[r][c] = X[(size_t)(ti * 64 + r) * DIMS + k0 + c];
            Bs[r][c] = X[(size_t)(tj * 64 + r) * DIMS + k0 + c];
        }
        __syncthreads();
        for (int k = 0; k < 16; k++) {
            float a[4], b[4];
            for (int e = 0; e < 4; e++) a[e] = As[ty * 4 + e][k];
            for (int f = 0; f < 4; f++) b[f] = Bs[tx * 4 + f][k];
            for (int e = 0; e < 4; e++)
                for (int f = 0; f < 4; f++) acc[e][f] += a[e] * b[f];
        }
        __syncthreads();
    }
    for (int e = 0; e < 4; e++)
        for (int f = 0; f < 4; f++) {
            int gi = ti * 64 + ty * 4 + e, gj = tj * 64 + tx * 4 + f;
            float d2 = sq[gi] + sq[gj] - 2.f * acc[e][f];
            out[(size_t)gi * N + gj] = sqrtf(fmaxf(d2, 0.f));
        }
}

// ---------------- KNN graph ----------------
__global__ void k_knn(const float* __restrict__ dist, float* __restrict__ G) {
    int i = blockIdx.x, t = threadIdx.x;
    float bv[6]; int bidx[6];
    for (int k = 0; k < 6; k++) { bv[k] = 3.4e38f; bidx[k] = N; }
    const float* dr = dist + (size_t)i * N;
    for (int j = t; j < N; j += 256) {
        float v = dr[j];
        bool ins = (v < bv[5]) || (v == bv[5] && j < bidx[5]);
        if (ins) {
            int k = 5;
            while (k > 0) {
                bool mv = (v < bv[k - 1]) || (v == bv[k - 1] && j < bidx[k - 1]);
                if (!mv) break;
                bv[k] = bv[k - 1]; bidx[k] = bidx[k - 1]; k--;
            }
            bv[k] = v; bidx[k] = j;
        }
    }
    __shared__ float lv[256][6]; __shared__ int li[256][6];
    for (int k = 0; k < 6; k++) { lv[t][k] = bv[k]; li[t][k] = bidx[k]; }
    __syncthreads();
    for (int off = 128; off >= 1; off >>= 1) {
        if (t < off) {
            float av[6], cv[6]; int ai[6], ci[6];
            for (int k = 0; k < 6; k++) { av[k] = lv[t][k]; ai[k] = li[t][k]; cv[k] = lv[t + off][k]; ci[k] = li[t + off][k]; }
            float mv[6]; int mi[6]; int pa = 0, pb = 0;
            for (int k = 0; k < 6; k++) {
                bool ta;
                if (pa >= 6) ta = false;
                else if (pb >= 6) ta = true;
                else ta = (av[pa] < cv[pb]) || (av[pa] == cv[pb] && ai[pa] < ci[pb]);
                if (ta) { mv[k] = av[pa]; mi[k] = ai[pa]; pa++; }
                else    { mv[k] = cv[pb]; mi[k] = ci[pb]; pb++; }
            }
            for (int k = 0; k < 6; k++) { lv[t][k] = mv[k]; li[t][k] = mi[k]; }
        }
        __syncthreads();
    }
    float sv[6]; int si[6];
    for (int k = 0; k < 6; k++) { sv[k] = lv[0][k]; si[k] = li[0][k]; }
    for (int j = t; j < N; j += 256) {
        float val = BIGV;
        for (int k = 0; k < 6; k++) if (j == si[k]) val = sv[k];
        G[(size_t)i * N + j] = val;
    }
}

__global__ void k_symdiag(float* __restrict__ G) {
    int idx = blockIdx.x * 256 + threadIdx.x;
    int i = idx >> 11, j = idx & 2047;
    if (i == j) { G[idx] = 0.f; return; }
    if (j > i) {
        float a = G[(size_t)i * N + j], b = G[(size_t)j * N + i];
        float m = fminf(a, b);
        G[(size_t)i * N + j] = m; G[(size_t)j * N + i] = m;
    }
}

// ---------------- blocked Floyd-Warshall ----------------
__global__ void __launch_bounds__(256) k_fw12(float* __restrict__ D, int kb) {
    __shared__ float KK[64][65], C[64][65];
    int bx = blockIdx.x, t = threadIdx.x;
    for (int e = 0; e < 16; e++) { int idx = t + e * 256; int r = idx >> 6, c = idx & 63;
        KK[r][c] = D[(size_t)(kb * 64 + r) * N + kb * 64 + c]; }
    __syncthreads();
    int r0 = t >> 2, c0 = (t & 3) * 16;
    for (int k = 0; k < 64; k++) {
        float dk = KK[r0][k];
        for (int c = 0; c < 16; c++) KK[r0][c0 + c] = fminf(KK[r0][c0 + c], dk + KK[k][c0 + c]);
        __syncthreads();
    }
    if (bx == 62) {
        for (int e = 0; e < 16; e++) { int idx = t + e * 256; int r = idx >> 6, c = idx & 63;
            D[(size_t)(kb * 64 + r) * N + kb * 64 + c] = KK[r][c]; }
        return;
    }
    bool rowstripe = bx < 31;
    int o = rowstripe ? bx : bx - 31;
    o += (o >= kb) ? 1 : 0;
    int baseR = rowstripe ? kb : o;
    int baseC = rowstripe ? o : kb;
    for (int e = 0; e < 16; e++) { int idx = t + e * 256; int r = idx >> 6, c = idx & 63;
        C[r][c] = D[(size_t)(baseR * 64 + r) * N + baseC * 64 + c]; }
    __syncthreads();
    if (rowstripe) {
        for (int k = 0; k < 64; k++) {
            float dk = KK[r0][k];
            for (int c = 0; c < 16; c++) C[r0][c0 + c] = fminf(C[r0][c0 + c], dk + C[k][c0 + c]);
            __syncthreads();
        }
    } else {
        for (int k = 0; k < 64; k++) {
            float dk = C[r0][k];
            for (int c = 0; c < 16; c++) C[r0][c0 + c] = fminf(C[r0][c0 + c], dk + KK[k][c0 + c]);
            __syncthreads();
        }
    }
    for (int e = 0; e < 16; e++) { int idx = t + e * 256; int r = idx >> 6, c = idx & 63;
        D[(size_t)(baseR * 64 + r) * N + baseC * 64 + c] = C[r][c]; }
}

__global__ void __launch_bounds__(256) k_fw3(float* __restrict__ D, int kb) {
    int bi = blockIdx.y, bj = blockIdx.x;
    if (bi == kb || bj == kb) return;
    __shared__ float R[64][65], Cl[64][65];
    int t = threadIdx.x;
    for (int e = 0; e < 16; e++) { int idx = t + e * 256; int r = idx >> 6, c = idx & 63;
        R[r][c]  = D[(size_t)(bi * 64 + r) * N + kb * 64 + c];
        Cl[r][c] = D[(size_t)(kb * 64 + r) * N + bj * 64 + c]; }
    __syncthreads();
    int r0 = (t >> 4) * 4, c0 = (t & 15) * 4;
    float acc[4][4];
    for (int e = 0; e < 4; e++) for (int f = 0; f < 4; f++) acc[e][f] = 3.4e38f;
    for (int k = 0; k < 64; k++) {
        float a[4], b[4];
        for (int e = 0; e < 4; e++) a[e] = R[r0 + e][k];
        for (int f = 0; f < 4; f++) b[f] = Cl[k][c0 + f];
        for (int e = 0; e < 4; e++)
            for (int f = 0; f < 4; f++) acc[e][f] = fminf(acc[e][f], a[e] + b[f]);
    }
    for (int e = 0; e < 4; e++)
        for (int f = 0; f < 4; f++) {
            size_t off = (size_t)(bi * 64 + r0 + e) * N + bj * 64 + c0 + f;
            D[off] = fminf(D[off], acc[e][f]);
        }
}

// ---------------- double centering ----------------
__global__ void k_rowmean(const float* __restrict__ D, double* __restrict__ rm) {
    int i = blockIdx.x, t = threadIdx.x;
    const float* dr = D + (size_t)i * N;
    double s = 0;
    for (int j = t; j < N; j += 256) { double d = (double)dr[j]; s += d * d; }
    __shared__ double red[256];
    red[t] = s; __syncthreads();
    for (int off = 128; off; off >>= 1) { if (t < off) red[t] += red[t + off]; __syncthreads(); }
    if (t == 0) rm[i] = red[0] / (double)N;
}

__global__ void k_grand(const double* __restrict__ rm, double* __restrict__ gm) {
    int t = threadIdx.x;
    double s = 0;
    for (int i = t; i < N; i += 256) s += rm[i];
    __shared__ double red[256];
    red[t] = s; __syncthreads();
    for (int off = 128; off; off >>= 1) { if (t < off) red[t] += red[t + off]; __syncthreads(); }
    if (t == 0) gm[0] = red[0] / (double)N;
}

__global__ void k_buildB(const float* __restrict__ D, const double* __restrict__ rm,
                         const double* __restrict__ gm, double* __restrict__ A) {
    int idx = blockIdx.x * 256 + threadIdx.x;
    int i = idx >> 11, j = idx & 2047;
    double d = (double)D[idx];
    A[idx] = -0.5 * (d * d - rm[i] - rm[j] + gm[0]);
}

__global__ void k_setV(float* __restrict__ V) {
    int idx = blockIdx.x * 256 + threadIdx.x;
    int i = idx >> 11, j = idx & 2047;
    V[idx] = (i == j) ? 1.f : 0.f;
}

// ---------------- Jacobi control flags ----------------
__global__ void k_initflags(unsigned* flags) { flags[0] = 0u; flags[1] = 0u; flags[2] = 0u; }
__global__ void k_sweepbegin(unsigned* flags) { if (!flags[2]) { flags[0] = 0u; flags[1] = 0u; } }
__global__ void k_sweepend(unsigned* flags) {
    if (!flags[2]) {
        float mo = __uint_as_float(flags[0]), md = __uint_as_float(flags[1]);
        if (mo <= 2e-9f * md) flags[2] = 1u;
    }
}

// ---------------- local 32x32 Jacobi on a team pair (fp64 M,Q) ----------------
// Single cyclic pass (31 micro-rounds x 16 rotations). Writes rotated diagonal
// tile back to A. LDS stride 33 doubles: bank=(2x+2y)%32 -> col/row access 2-way (free).
__global__ void __launch_bounds__(256) k_local(double* __restrict__ A, double* __restrict__ qb,
                                               int* __restrict__ qfl, unsigned* __restrict__ flags,
                                               int round) {
    int p = blockIdx.x, t = threadIdx.x;
    if (flags[2]) { if (t == 0) qfl[p] = 0; return; }
    __shared__ double M[32][33], Q[32][33];
    __shared__ double cA[16], sA[16];
    __shared__ int ppA[16], qqA[16];
    __shared__ float red1[256], red2[256];
    __shared__ int everr;
    int bi, bj; rr_pairN(round, p, NB, bi, bj);

    float offm = 0.f, diagm = 0.f;
    for (int e = 0; e < 4; e++) {
        int idx = t + e * 256; int x = idx >> 5, y = idx & 31;
        int gr = (x < 16) ? bi * 16 + x : bj * 16 + (x - 16);
        int gc = (y < 16) ? bi * 16 + y : bj * 16 + (y - 16);
        double v = A[(size_t)gr * N + gc];
        M[x][y] = v;
        float av = (float)fabs(v);
        if (x == y) diagm = fmaxf(diagm, av); else offm = fmaxf(offm, av);
        Q[x][y] = (x == y) ? 1.0 : 0.0;
    }
    red1[t] = offm; red2[t] = diagm;
    if (t == 0) everr = 0;
    __syncthreads();
    for (int off = 128; off; off >>= 1) {
        if (t < off) { red1[t] = fmaxf(red1[t], red1[t + off]); red2[t] = fmaxf(red2[t], red2[t + off]); }
        __syncthreads();
    }
    float dmaxf = red2[0], off0 = red1[0];
    if (t == 0) { atomicMax(flags + 0, __float_as_uint(off0)); atomicMax(flags + 1, __float_as_uint(dmaxf)); }
    double dmax = (double)dmaxf;
    if ((double)off0 <= 1e-9 * dmax) { if (t == 0) qfl[p] = 0; return; }
    double thr = fmax(1e-13 * dmax, 1e-5 * (double)off0);

    for (int ir = 0; ir < 31; ir++) {
        if (t < 16) {
            int pp, qq; rr_pairN(ir, t, 32, pp, qq);
            double app = M[pp][pp], aqq = M[qq][qq], apq = M[pp][qq];
            double c = 1.0, sn = 0.0;
            if (fabs(apq) > thr) {
                double tau = (aqq - app) / (2.0 * apq);
                double tt2 = ((tau >= 0.0) ? 1.0 : -1.0) / (fabs(tau) + sqrt(1.0 + tau * tau));
                c = 1.0 / sqrt(1.0 + tt2 * tt2);
                sn = tt2 * c;
                everr = 1;
            }
            ppA[t] = pp; qqA[t] = qq; cA[t] = c; sA[t] = sn;
        }
        __syncthreads();
        // col updates: M <- M*J, Q <- Q*J  (512 slots, 2/thread)
        for (int e = 0; e < 2; e++) {
            int slot = t + e * 256; int mm = slot >> 5, k = slot & 31;
            double sn = sA[mm];
            if (sn != 0.0) {
                int pp = ppA[mm], qq = qqA[mm]; double c = cA[mm];
                double a = M[k][pp], b = M[k][qq];
                M[k][pp] = c * a - sn * b; M[k][qq] = sn * a + c * b;
                a = Q[k][pp]; b = Q[k][qq];
                Q[k][pp] = c * a - sn * b; Q[k][qq] = sn * a + c * b;
            }
        }
        __syncthreads();
        // row updates: M <- J^T * M
        for (int e = 0; e < 2; e++) {
            int slot = t + e * 256; int mm = slot >> 5, k = slot & 31;
            double sn = sA[mm];
            if (sn != 0.0) {
                int pp = ppA[mm], qq = qqA[mm]; double c = cA[mm];
                double a = M[pp][k], b = M[qq][k];
                M[pp][k] = c * a - sn * b; M[qq][k] = sn * a + c * b;
            }
        }
        __syncthreads();
    }
    int ev = everr;
    if (t == 0) qfl[p] = ev;
    if (ev) {
        for (int e = 0; e < 4; e++) {
            int idx = t + e * 256; int x = idx >> 5, y = idx & 31;
            qb[(size_t)p * 1024 + idx] = Q[x][y];
            int gr = (x < 16) ? bi * 16 + x : bj * 16 + (x - 16);
            int gc = (y < 16) ? bi * 16 + y : bj * 16 + (y - 16);
            A[(size_t)gr * N + gc] = M[x][y];
        }
    }
}

// fused apply. z=0: A <- Qr^T A Qc on upper-tri pair tiles (pr<pc), 32x32 fp64,
//   two-phase Q staging, writes tile + mirror. z=1: V <- V*Q (f32, 64-row stripes).
__global__ void __launch_bounds__(256) k_apply(double* __restrict__ A, float* __restrict__ V,
                                               const double* __restrict__ qb,
                                               const int* __restrict__ qfl,
                                               const unsigned* __restrict__ flags, int round) {
    if (flags[2]) return;
    int t = threadIdx.x;
    if (blockIdx.z == 0) {
        int pr = blockIdx.y, pc = blockIdx.x;
        if (pr >= pc) return;
        int fr = qfl[pr], fc = qfl[pc];
        if (!fr && !fc) return;
        __shared__ double T[32][33], Qb[32][33];
        int bir, bjr, bic, bjc;
        rr_pairN(round, pr, NB, bir, bjr);
        rr_pairN(round, pc, NB, bic, bjc);
        for (int e = 0; e < 4; e++) {
            int idx = t + e * 256; int a = idx >> 5, b = idx & 31;
            if (fr) Qb[a][b] = qb[(size_t)pr * 1024 + idx];
            int gr = (a < 16) ? bir * 16 + a : bjr * 16 + (a - 16);
            int gc = (b < 16) ? bic * 16 + b : bjc * 16 + (b - 16);
            T[a][b] = A[(size_t)gr * N + gc];
        }
        __syncthreads();
        int x0 = (t >> 4) * 2, c0 = (t & 15) * 2;
        if (fr) {
            double acc[2][2] = {};
            for (int y = 0; y < 32; y++) {
                double q0 = Qb[y][x0], q1 = Qb[y][x0 + 1];
                double v0 = T[y][c0], v1 = T[y][c0 + 1];
                acc[0][0] += q0 * v0; acc[0][1] += q0 * v1;
                acc[1][0] += q1 * v0; acc[1][1] += q1 * v1;
            }
            __syncthreads();
            T[x0][c0] = acc[0][0]; T[x0][c0 + 1] = acc[0][1];
            T[x0 + 1][c0] = acc[1][0]; T[x0 + 1][c0 + 1] = acc[1][1];
            __syncthreads();
        }
        if (fc) {
            for (int e = 0; e < 4; e++) {
                int idx = t + e * 256; int a = idx >> 5, b = idx & 31;
                Qb[a][b] = qb[(size_t)pc * 1024 + idx];
            }
            __syncthreads();
            double acc[2][2] = {};
            for (int y = 0; y < 32; y++) {
                double v0 = T[x0][y], v1 = T[x0 + 1][y];
                double q0 = Qb[y][c0], q1 = Qb[y][c0 + 1];
                acc[0][0] += v0 * q0; acc[0][1] += v0 * q1;
                acc[1][0] += v1 * q0; acc[1][1] += v1 * q1;
            }
            __syncthreads();
            T[x0][c0] = acc[0][0]; T[x0][c0 + 1] = acc[0][1];
            T[x0 + 1][c0] = acc[1][0]; T[x0 + 1][c0 + 1] = acc[1][1];
            __syncthreads();
        }
        for (int e = 0; e < 4; e++) {
            int idx = t + e * 256; int a = idx >> 5, b = idx & 31;
            int gr = (a < 16) ? bir * 16 + a : bjr * 16 + (a - 16);
            int gc = (b < 16) ? bic * 16 + b : bjc * 16 + (b - 16);
            A[(size_t)gr * N + gc] = T[a][b];
            int gr2 = (a < 16) ? bic * 16 + a : bjc * 16 + (a - 16);
            int gc2 = (b < 16) ? bir * 16 + b : bjr * 16 + (b - 16);
            A[(size_t)gr2 * N + gc2] = T[b][a];
        }
    } else {
        int p = blockIdx.y, rt = blockIdx.x;
        if (rt >= 32) return;
        if (!qfl[p]) return;
        __shared__ float Qs[32][33], Tv[64][33];
        int bi, bj; rr_pairN(round, p, NB, bi, bj);
        for (int e = 0; e < 4; e++) {
            int idx = t + e * 256; int a = idx >> 5, b = idx & 31;
            Qs[a][b] = (float)qb[(size_t)p * 1024 + idx];
        }
        for (int e = 0; e < 8; e++) {
            int idx = t + e * 256; int a = idx >> 5, b = idx & 31;
            int gc = (b < 16) ? bi * 16 + b : bj * 16 + (b - 16);
            Tv[a][b] = V[(size_t)(rt * 64 + a) * N + gc];
        }
        __syncthreads();
        int r0 = (t >> 4) * 4, c0 = (t & 15) * 2;
        float acc[4][2] = {};
        for (int y = 0; y < 32; y++) {
            float q0 = Qs[y][c0], q1 = Qs[y][c0 + 1];
            for (int e = 0; e < 4; e++) {
                float vv = Tv[r0 + e][y];
                acc[e][0] += vv * q0; acc[e][1] += vv * q1;
            }
        }
        for (int e = 0; e < 4; e++)
            for (int f = 0; f < 2; f++) {
                int x = c0 + f;
                int gc = (x < 16) ? bi * 16 + x : bj * 16 + (x - 16);
                V[(size_t)(rt * 64 + r0 + e) * N + gc] = acc[e][f];
            }
    }
}

// ---------------- epilogue ----------------
__global__ void k_lambda(const double* __restrict__ A, double* __restrict__ lam) {
    int i = blockIdx.x * 256 + threadIdx.x;
    if (i < N) lam[i] = A[(size_t)i * N + i];
}

__global__ void __launch_bounds__(1024) k_sort(const double* __restrict__ lam,
                                               double* __restrict__ lams, int* __restrict__ order) {
    __shared__ double v[2048]; __shared__ int ix[2048];
    int t = threadIdx.x;
    v[t] = lam[t]; v[t + 1024] = lam[t + 1024];
    ix[t] = t; ix[t + 1024] = t + 1024;
    __syncthreads();
    for (int k = 2; k <= 2048; k <<= 1) {
        for (int j = k >> 1; j > 0; j >>= 1) {
            int l = ((t & ~(j - 1)) << 1) | (t & (j - 1));
            int partner = l | j;
            double va = v[l], vb = v[partner]; int ia = ix[l], ib = ix[partner];
            bool before = (va > vb) || (va == vb && ia < ib);
            bool asc = ((l & k) == 0);
            bool doSwap = asc ? (!before) : before;
            if (doSwap) { v[l] = vb; v[partner] = va; ix[l] = ib; ix[partner] = ia; }
            __syncthreads();
        }
    }
    lams[t] = v[t]; lams[t + 1024] = v[t + 1024];
    order[t] = ix[t]; order[t + 1024] = ix[t + 1024];
}

__global__ void k_out(const float* __restrict__ Vm, const double* __restrict__ lams,
                      const int* __restrict__ order, float* __restrict__ out) {
    int c = blockIdx.x, t = threadIdx.x;
    int col = order[c];
    __shared__ float rv[256]; __shared__ int ri[256];
    float bv = -1.f; int bidx = N;
    for (int i = t; i < N; i += 256) {
        float av = fabsf(Vm[(size_t)i * N + col]);
        if (av > bv || (av == bv && i < bidx)) { bv = av; bidx = i; }
    }
    rv[t] = bv; ri[t] = bidx;
    __syncthreads();
    for (int off = 128; off; off >>= 1) {
        if (t < off) {
            if (rv[t + off] > rv[t] || (rv[t + off] == rv[t] && ri[t + off] < ri[t])) {
                rv[t] = rv[t + off]; ri[t] = ri[t + off];
            }
        }
        __syncthreads();
    }
    float sv = Vm[(size_t)ri[0] * N + col];
    float s = (sv > 0.f) ? 1.f : ((sv < 0.f) ? -1.f : 0.f);
    double lv = lams[c];
    float f = s * (float)sqrt(lv > 0.0 ? lv : 0.0);
    for (int i = t; i < N; i += 256) out[(size_t)i * NC + c] = Vm[(size_t)i * N + col] * f;
}

extern "C" void kernel_launch(void* const* d_in, const int* in_sizes, int n_in,
                              void* d_out, int out_size, void* d_ws, size_t ws_size,
                              hipStream_t stream) {
    (void)in_sizes; (void)n_in; (void)out_size; (void)ws_size;
    const float* X = (const float*)d_in[0];
    float* out = (float*)d_out;

    double* rm  = (double*)d_ws;                 // N
    double* gm  = rm + N;                        // 1 (+7 pad)
    double* lam = gm + 8;                        // N
    double* lams= lam + N;                       // N
    double* A   = lams + N;                      // N*N fp64
    double* qb  = A + (size_t)N * N;             // NPAIRS*1024 fp64
    float* Dg   = (float*)(qb + (size_t)NPAIRS * 1024); // N*N f32
    float* Vm   = Dg + (size_t)N * N;            // N*N f32
    float* sq   = Vm + (size_t)N * N;            // N
    int* order  = (int*)(sq + N);                // N
    int* qfl    = order + N;                     // NPAIRS
    unsigned* flags = (unsigned*)(qfl + NPAIRS); // 3
    float* dist = (float*)A;                     // alias: dist dies before A is born

    // 1. pairwise distances
    k_rowsq<<<N / 4, 256, 0, stream>>>(X, sq);
    k_dist<<<dim3(32, 32), 256, 0, stream>>>(X, sq, dist);

    // 2. KNN graph
    k_knn<<<N, 256, 0, stream>>>(dist, Dg);
    k_symdiag<<<(N * N) / 256, 256, 0, stream>>>(Dg);

    // 3. blocked Floyd-Warshall
    for (int kb = 0; kb < N / 64; kb++) {
        k_fw12<<<63, 256, 0, stream>>>(Dg, kb);
        k_fw3<<<dim3(32, 32), 256, 0, stream>>>(Dg, kb);
    }

    // 4. double centering -> B (fp64)
    k_rowmean<<<N, 256, 0, stream>>>(Dg, rm);
    k_grand<<<1, 256, 0, stream>>>(rm, gm);
    k_buildB<<<(N * N) / 256, 256, 0, stream>>>(Dg, rm, gm, A);
    k_setV<<<(N * N) / 256, 256, 0, stream>>>(Vm);
    k_initflags<<<1, 1, 0, stream>>>(flags);

    // 5. two-sided block Jacobi (128 teams of 16, 32x32 tiles, single inner pass)
    for (int sw = 0; sw < NSWEEPS; sw++) {
        k_sweepbegin<<<1, 1, 0, stream>>>(flags);
        for (int r = 0; r < NB - 1; r++) {
            k_local<<<NPAIRS, 256, 0, stream>>>(A, qb, qfl, flags, r);
            k_apply<<<dim3(NPAIRS, NPAIRS, 2), 256, 0, stream>>>(A, Vm, qb, qfl, flags, r);
        }
        k_sweepend<<<1, 1, 0, stream>>>(flags);
    }

    // 6. sort eigenvalues, sign-fix, scale, write output
    k_lambda<<<N / 256, 256, 0, stream>>>(A, lam);
    k_sort<<<1, 1024, 0, stream>>>(lam, lams, order);
    k_out<<<NC, 256, 0, stream>>>(Vm, lams, order, out);
}